// Round 1
// baseline (465.666 us; speedup 1.0000x reference)
//
#include <hip/hip_runtime.h>
#include <hip/hip_bf16.h>

// Lukasiewicz t-norm feature expansion:
//   out[:, 0:16]    = x
//   out[:, 16:136]  = max(x[a]+x[b] - 1, 0)        for (a,b)   lex combos of 16
//   out[:, 136:696] = max(x[a]+x[b]+x[c] - 2, 0)   for (a,b,c) lex combos of 16
// N = 131072 rows, 696 output cols. Write-BW bound (~365 MB out).

#define NCOLS 696

struct ColTab { unsigned int v[NCOLS]; };

// Packed descriptor per output column:
//   bits [4:0]   = a  (index into xl, 16 == zero slot)
//   bits [9:5]   = b
//   bits [14:10] = c
//   bits [16:15] = bias (i-1)
// Column order matches itertools.combinations (lexicographic).
constexpr ColTab make_tab() {
    ColTab t{};
    int k = 0;
    for (int a = 0; a < 16; ++a)
        t.v[k++] = (unsigned)a | (16u << 5) | (16u << 10) | (0u << 15);
    for (int a = 0; a < 16; ++a)
        for (int b = a + 1; b < 16; ++b)
            t.v[k++] = (unsigned)a | ((unsigned)b << 5) | (16u << 10) | (1u << 15);
    for (int a = 0; a < 16; ++a)
        for (int b = a + 1; b < 16; ++b)
            for (int c = b + 1; c < 16; ++c)
                t.v[k++] = (unsigned)a | ((unsigned)b << 5) | ((unsigned)c << 10) | (2u << 15);
    return t;
}

__constant__ ColTab g_tab = make_tab();

__global__ __launch_bounds__(256) void luk_kernel(const float* __restrict__ x,
                                                  float* __restrict__ out) {
    __shared__ float xl[17];   // 16 row values + zero slot
    const int row = blockIdx.x;
    const int t   = threadIdx.x;

    if (t < 4) {
        const float4 v = reinterpret_cast<const float4*>(x + (size_t)row * 16)[t];
        xl[t * 4 + 0] = v.x;
        xl[t * 4 + 1] = v.y;
        xl[t * 4 + 2] = v.z;
        xl[t * 4 + 3] = v.w;
    }
    if (t == 4) xl[16] = 0.0f;
    __syncthreads();

    float* orow = out + (size_t)row * NCOLS;

    #pragma unroll
    for (int base = 0; base < NCOLS; base += 256) {
        const int c = base + t;
        if (c < NCOLS) {
            const unsigned v = g_tab.v[c];
            const float s = xl[v & 31u] + xl[(v >> 5) & 31u] + xl[(v >> 10) & 31u]
                          - (float)((v >> 15) & 3u);
            orow[c] = fmaxf(s, 0.0f);
        }
    }
}

extern "C" void kernel_launch(void* const* d_in, const int* in_sizes, int n_in,
                              void* d_out, int out_size, void* d_ws, size_t ws_size,
                              hipStream_t stream) {
    const float* x = (const float*)d_in[0];
    float* out = (float*)d_out;
    const int nrows = in_sizes[0] / 16;   // 131072
    luk_kernel<<<nrows, 256, 0, stream>>>(x, out);
}

// Round 2
// 368.932 us; speedup vs baseline: 1.2622x; 1.2622x over previous
//
#include <hip/hip_runtime.h>
#include <hip/hip_bf16.h>

// Lukasiewicz t-norm feature expansion, write-BW-bound (~365 MB out).
//   out[:, 0:16]    = x
//   out[:, 16:136]  = max(x[a]+x[b] - 1, 0)        (a,b)   lex combos of 16
//   out[:, 136:696] = max(x[a]+x[b]+x[c] - 2, 0)   (a,b,c) lex combos of 16
//
// R2 design: 2048 fat blocks, grid-stride over 16-row tiles, float4 NT stores.
// R1 (block-per-row, dword stores) was latency-bound at 465 us (~0.8 TB/s).

#define NCOLS 696
#define NC4   174          // NCOLS / 4
#define RPT   16           // rows per tile
#define NQUADS (RPT * NC4) // 2784 float4 stores per tile

typedef float v4f __attribute__((ext_vector_type(4)));

struct ColTab { unsigned int v[NCOLS]; };

// Packed per-column descriptor: a[4:0] | b[9:5] | c[14:10] | bias[16:15]
// index 16 -> zero slot. Order matches itertools.combinations (lex).
constexpr ColTab make_tab() {
    ColTab t{};
    int k = 0;
    for (int a = 0; a < 16; ++a)
        t.v[k++] = (unsigned)a | (16u << 5) | (16u << 10);
    for (int a = 0; a < 16; ++a)
        for (int b = a + 1; b < 16; ++b)
            t.v[k++] = (unsigned)a | ((unsigned)b << 5) | (16u << 10) | (1u << 15);
    for (int a = 0; a < 16; ++a)
        for (int b = a + 1; b < 16; ++b)
            for (int c = b + 1; c < 16; ++c)
                t.v[k++] = (unsigned)a | ((unsigned)b << 5) | ((unsigned)c << 10) | (2u << 15);
    return t;
}

__constant__ ColTab g_tab = make_tab();

__device__ __forceinline__ float tnorm(const float* __restrict__ xr, unsigned v) {
    return fmaxf(xr[v & 31u] + xr[(v >> 5) & 31u] + xr[(v >> 10) & 31u]
                 - (float)((v >> 15) & 3u), 0.0f);
}

__global__ __launch_bounds__(256) void luk_kernel(const float* __restrict__ x,
                                                  float* __restrict__ out,
                                                  int nrows, int ntiles) {
    // 16 rows * (16 vals + zero slot), stride 17: intra-row reads hit 17
    // distinct banks (same-addr broadcasts free); cross-row aliasing <=2-way.
    __shared__ float xl[RPT * 17];
    const int t = threadIdx.x;
    const uint4* __restrict__ tab4 = reinterpret_cast<const uint4*>(g_tab.v);

    for (int tile = blockIdx.x; tile < ntiles; tile += gridDim.x) {
        const int row0 = tile * RPT;
        const int rlim = min(RPT, nrows - row0);

        {   // cooperative coalesced load: 256 consecutive floats
            const int r = t >> 4, a = t & 15;
            float v = 0.0f;
            if (r < rlim) v = x[(size_t)row0 * 16 + t];
            xl[r * 17 + a] = v;
            if (t < RPT) xl[t * 17 + 16] = 0.0f;
        }
        __syncthreads();

        const int nq = rlim * NC4;
        for (int i = t; i < nq; i += 256) {
            const int r  = (unsigned)i / (unsigned)NC4;
            const int c4 = i - r * NC4;
            const uint4 tv = tab4[c4];
            const float* __restrict__ xr = &xl[r * 17];
            v4f o;
            o.x = tnorm(xr, tv.x);
            o.y = tnorm(xr, tv.y);
            o.z = tnorm(xr, tv.z);
            o.w = tnorm(xr, tv.w);
            v4f* dst = reinterpret_cast<v4f*>(out + (size_t)(row0 + r) * NCOLS) + c4;
            __builtin_nontemporal_store(o, dst);
        }
        __syncthreads();   // xl reused next tile
    }
}

extern "C" void kernel_launch(void* const* d_in, const int* in_sizes, int n_in,
                              void* d_out, int out_size, void* d_ws, size_t ws_size,
                              hipStream_t stream) {
    const float* x = (const float*)d_in[0];
    float* out = (float*)d_out;
    const int nrows  = in_sizes[0] / 16;           // 131072
    const int ntiles = (nrows + RPT - 1) / RPT;    // 8192
    const int blocks = ntiles < 2048 ? ntiles : 2048;  // 8 blocks/CU
    luk_kernel<<<blocks, 256, 0, stream>>>(x, out, nrows, ntiles);
}